// Round 8
// baseline (401.620 us; speedup 1.0000x reference)
//
#include <hip/hip_runtime.h>
#include <cstddef>

#define NB 4
#define SEQL 2048
#define DMODEL 768
#define DSTATE 128
#define HEADDIM 64
#define NHEADS 24
#define DINNER 1536
#define CONVDIM 1792
#define DINPROJ 3352
#define BLROWS (NB*SEQL)
#define RMS_EPS 1e-5f
#define Q 128
#define NC (SEQL/Q)
#define BOFF DINNER
#define COFF (DINNER + DSTATE)
#define BK 64

typedef unsigned int uint;
typedef unsigned short ushort;
typedef __attribute__((ext_vector_type(8))) short bf16x8;
typedef __attribute__((ext_vector_type(4))) float f32x4;

__device__ __forceinline__ float sigmoidf_(float x){ return 1.f/(1.f+expf(-x)); }
__device__ __forceinline__ float siluf_(float x){ return x * sigmoidf_(x); }
__device__ __forceinline__ float softplusf_(float x){ return x > 20.f ? x : log1pf(expf(x)); }

__device__ __forceinline__ ushort f2bf(float f){
    union { float f; uint u; } v; v.f = f;
    uint r = (v.u + 0x7FFFu + ((v.u >> 16) & 1u)) >> 16;
    return (ushort)r;
}
__device__ __forceinline__ float bf2f(ushort s){
    union { uint u; float f; } v; v.u = ((uint)s) << 16;
    return v.f;
}
__device__ __forceinline__ uint pack2(float a, float b){
    return (uint)f2bf(a) | ((uint)f2bf(b) << 16);
}
__device__ __forceinline__ void unpack8(uint4 r, float* o){
    o[0]=bf2f((ushort)(r.x&0xffff)); o[1]=bf2f((ushort)(r.x>>16));
    o[2]=bf2f((ushort)(r.y&0xffff)); o[3]=bf2f((ushort)(r.y>>16));
    o[4]=bf2f((ushort)(r.z&0xffff)); o[5]=bf2f((ushort)(r.z>>16));
    o[6]=bf2f((ushort)(r.w&0xffff)); o[7]=bf2f((ushort)(r.w>>16));
}
__device__ __forceinline__ uint packu2(ushort a, ushort b){
    return (uint)a | ((uint)b << 16);
}

#define GLD16(g, l) __builtin_amdgcn_global_load_lds( \
    (const __attribute__((address_space(1))) void*)(g), \
    (__attribute__((address_space(3))) void*)(l), 16, 0, 0)

// ---------------- fp32 -> bf16 cast
__global__ __launch_bounds__(256) void cast_kernel(
    const float* __restrict__ in, ushort* __restrict__ out, int n4)
{
    const int i = blockIdx.x*256 + threadIdx.x;
    if (i < n4) {
        float4 v = ((const float4*)in)[i];
        ushort4 o = make_ushort4(f2bf(v.x), f2bf(v.y), f2bf(v.z), f2bf(v.w));
        ((ushort4*)out)[i] = o;
    }
}

// ---------------- MFMA GEMM, fp32 out (out_proj): C = A @ W^T.
// A: GLD16 -> swizzled LDS. W: direct global->VGPR fragments (no LDS).
// grid: (M/128, N/128), blockIdx.x = m-block for W L2 locality.
__global__ __launch_bounds__(256) void gemm_mfma(
    const ushort* __restrict__ A, const ushort* __restrict__ W,
    float* __restrict__ C, int M, int N, int K, const float* __restrict__ gptr)
{
    __shared__ __align__(16) ushort As[128*BK];
    const int tid = threadIdx.x;
    const int wv = tid >> 6, ln = tid & 63;
    const int m0 = blockIdx.x * 128, n0 = blockIdx.y * 128;
    const int wm = (wv >> 1) * 64, wn = (wv & 1) * 64;

    const int sr = ln >> 3;
    const int scol = ((ln & 7) ^ sr) * 8;
    const ushort* gA[4];
    ushort* lA[4];
#pragma unroll
    for (int iss = 0; iss < 4; ++iss) {
        gA[iss] = A + (size_t)(m0 + wv*32 + iss*8 + sr) * K + scol;
        lA[iss] = &As[(wv*32 + iss*8) * BK];
    }
    const int fr = ln & 15, fq = ln >> 4;
    const ushort* gW[4];
#pragma unroll
    for (int j = 0; j < 4; ++j) {
        int rb = n0 + wn + j*16 + fr; if (rb >= N) rb = N - 1;
        gW[j] = W + (size_t)rb * K + fq*8;
    }

    f32x4 acc[4][4];
#pragma unroll
    for (int i = 0; i < 4; ++i)
#pragma unroll
        for (int j = 0; j < 4; ++j) acc[i][j] = (f32x4){0.f, 0.f, 0.f, 0.f};

    for (int kt = 0; kt < K; kt += BK) {
        __syncthreads();
#pragma unroll
        for (int iss = 0; iss < 4; ++iss) GLD16(gA[iss] + kt, lA[iss]);
        bf16x8 bfr[2][4];
#pragma unroll
        for (int kh = 0; kh < 2; ++kh)
#pragma unroll
            for (int j = 0; j < 4; ++j)
                bfr[kh][j] = *(const bf16x8*)(gW[j] + kt + kh*32);
        __syncthreads();
#pragma unroll
        for (int kh = 0; kh < 2; ++kh) {
            const int sw = ((kh*4 + fq) ^ (fr & 7)) * 8;
            bf16x8 af[4];
#pragma unroll
            for (int i = 0; i < 4; ++i)
                af[i] = *(const bf16x8*)&As[(wm + i*16 + fr)*BK + sw];
#pragma unroll
            for (int i = 0; i < 4; ++i)
#pragma unroll
                for (int j = 0; j < 4; ++j)
                    acc[i][j] = __builtin_amdgcn_mfma_f32_16x16x32_bf16(af[i], bfr[kh][j], acc[i][j], 0, 0, 0);
        }
    }

    float scale = 1.f;
    if (gptr) scale = sigmoidf_(*gptr);
    const int cn = ln & 15;
    const int cr = (ln >> 4) * 4;
#pragma unroll
    for (int i = 0; i < 4; ++i) {
        const int mb = m0 + wm + i*16 + cr;
#pragma unroll
        for (int j = 0; j < 4; ++j) {
            const int n = n0 + wn + j*16 + cn;
            if (n < N) {
                float* cp = C + (size_t)mb * N + n;
                cp[0*(size_t)N] = acc[i][j].x * scale;
                cp[1*(size_t)N] = acc[i][j].y * scale;
                cp[2*(size_t)N] = acc[i][j].z * scale;
                cp[3*(size_t)N] = acc[i][j].w * scale;
            }
        }
    }
}

// ---------------- MFMA GEMM, bf16 out via LDS repack (in_proj); dt cols -> fp32 dtraw.
__global__ __launch_bounds__(256) void gemm_mfma_bf16o(
    const ushort* __restrict__ A, const ushort* __restrict__ W,
    ushort* __restrict__ C, float* __restrict__ dtraw, int M, int N, int K)
{
    __shared__ __align__(16) ushort sm[16384];   // 32 KB: As staging (16 KB) ; repack aliases
    ushort* As = sm;
    const int tid = threadIdx.x;
    const int wv = tid >> 6, ln = tid & 63;
    const int m0 = blockIdx.x * 128, n0 = blockIdx.y * 128;
    const int wm = (wv >> 1) * 64, wn = (wv & 1) * 64;

    const int sr = ln >> 3;
    const int scol = ((ln & 7) ^ sr) * 8;
    const ushort* gA[4];
    ushort* lA[4];
#pragma unroll
    for (int iss = 0; iss < 4; ++iss) {
        gA[iss] = A + (size_t)(m0 + wv*32 + iss*8 + sr) * K + scol;
        lA[iss] = &As[(wv*32 + iss*8) * BK];
    }
    const int fr = ln & 15, fq = ln >> 4;
    const ushort* gW[4];
#pragma unroll
    for (int j = 0; j < 4; ++j) {
        int rb = n0 + wn + j*16 + fr; if (rb >= N) rb = N - 1;
        gW[j] = W + (size_t)rb * K + fq*8;
    }

    f32x4 acc[4][4];
#pragma unroll
    for (int i = 0; i < 4; ++i)
#pragma unroll
        for (int j = 0; j < 4; ++j) acc[i][j] = (f32x4){0.f, 0.f, 0.f, 0.f};

    for (int kt = 0; kt < K; kt += BK) {
        __syncthreads();
#pragma unroll
        for (int iss = 0; iss < 4; ++iss) GLD16(gA[iss] + kt, lA[iss]);
        bf16x8 bfr[2][4];
#pragma unroll
        for (int kh = 0; kh < 2; ++kh)
#pragma unroll
            for (int j = 0; j < 4; ++j)
                bfr[kh][j] = *(const bf16x8*)(gW[j] + kt + kh*32);
        __syncthreads();
#pragma unroll
        for (int kh = 0; kh < 2; ++kh) {
            const int sw = ((kh*4 + fq) ^ (fr & 7)) * 8;
            bf16x8 af[4];
#pragma unroll
            for (int i = 0; i < 4; ++i)
                af[i] = *(const bf16x8*)&As[(wm + i*16 + fr)*BK + sw];
#pragma unroll
            for (int i = 0; i < 4; ++i)
#pragma unroll
                for (int j = 0; j < 4; ++j)
                    acc[i][j] = __builtin_amdgcn_mfma_f32_16x16x32_bf16(af[i], bfr[kh][j], acc[i][j], 0, 0, 0);
        }
    }

    const int cn = ln & 15;
    const int cr = (ln >> 4) * 4;
    __syncthreads();                       // staging LDS dead -> repack
    ushort* rp = sm + wv*4096;             // 64 rows x 64 cols per wave
#pragma unroll
    for (int i = 0; i < 4; ++i)
#pragma unroll
        for (int j = 0; j < 4; ++j) {
            const int col = j*16 + cn;
#pragma unroll
            for (int r = 0; r < 4; ++r)
                rp[(i*16 + cr + r)*64 + col] = f2bf(acc[i][j][r]);
        }
    __syncthreads();
#pragma unroll
    for (int k2 = 0; k2 < 8; ++k2) {
        const int row = k2*8 + (ln >> 3);
        uint4 v = *(const uint4*)&rp[row*64 + (ln & 7)*8];
        const int gm = m0 + wm + row;
        const int gn = n0 + wn + (ln & 7)*8;
        if (gn + 8 <= N)
            *(uint4*)(C + (size_t)gm*N + gn) = v;
    }
    if (n0 + 128 > N) {
#pragma unroll
        for (int i = 0; i < 4; ++i) {
            const int mb = m0 + wm + i*16 + cr;
#pragma unroll
            for (int j = 0; j < 4; ++j) {
                const int col = (n0 + wn + j*16 + cn) - (N - 24);
                if (col >= 0 && col < 24) {
                    dtraw[(size_t)(mb+0)*24 + col] = acc[i][j].x;
                    dtraw[(size_t)(mb+1)*24 + col] = acc[i][j].y;
                    dtraw[(size_t)(mb+2)*24 + col] = acc[i][j].z;
                    dtraw[(size_t)(mb+3)*24 + col] = acc[i][j].w;
                }
            }
        }
    }
}

// ---------------- causal depthwise conv1d + bias + silu (bf16 in/out)
__global__ __launch_bounds__(448) void conv_kernel(
    const ushort* __restrict__ zx, const float* __restrict__ conv_w,
    const float* __restrict__ conv_b, ushort* __restrict__ xconv)
{
    const int c4 = threadIdx.x;
    const int bl = blockIdx.x;
    const int l = bl & (SEQL - 1);
    float w[4][4];
#pragma unroll
    for (int j = 0; j < 4; ++j) {
        float4 wr = *(const float4*)(conv_w + (c4*4 + j)*4);
        w[j][0]=wr.x; w[j][1]=wr.y; w[j][2]=wr.z; w[j][3]=wr.w;
    }
    float4 bias = *(const float4*)(conv_b + c4*4);
    float s[4] = {bias.x, bias.y, bias.z, bias.w};
#pragma unroll
    for (int k = 0; k < 4; ++k) {
        const int ls = l - 3 + k;
        if (ls >= 0) {
            ushort4 xv = *(const ushort4*)(zx + (size_t)(bl - 3 + k)*DINPROJ + DINNER + c4*4);
            s[0] = fmaf(bf2f(xv.x), w[0][k], s[0]);
            s[1] = fmaf(bf2f(xv.y), w[1][k], s[1]);
            s[2] = fmaf(bf2f(xv.z), w[2][k], s[2]);
            s[3] = fmaf(bf2f(xv.w), w[3][k], s[3]);
        }
    }
    ushort4 o = make_ushort4(f2bf(siluf_(s[0])), f2bf(siluf_(s[1])),
                             f2bf(siluf_(s[2])), f2bf(siluf_(s[3])));
    *(ushort4*)(xconv + (size_t)bl*CONVDIM + c4*4) = o;
}

// ---------------- dt = softplus(dt+bias); clog = chunk-local inclusive cumsum of A*dt
__global__ __launch_bounds__(128) void dtscan_kernel(
    const float* __restrict__ dtraw, const float* __restrict__ dt_bias,
    const float* __restrict__ A_log, float* __restrict__ dtc, float* __restrict__ clog)
{
    const int c = blockIdx.x, h = blockIdx.y, b = blockIdx.z;
    const int t = threadIdx.x;
    const int bl = b*SEQL + c*Q + t;
    float draw = dtraw[(size_t)bl*24 + h] + dt_bias[h];
    float dtv = softplusf_(draw);
    float la = -expf(A_log[h]) * dtv;
    const int lane = t & 63;
    float v = la;
#pragma unroll
    for (int off = 1; off < 64; off <<= 1) {
        float u = __shfl_up(v, off);
        if (lane >= off) v += u;
    }
    __shared__ float w0tot;
    if (t == 63) w0tot = v;
    __syncthreads();
    if (t >= 64) v += w0tot;
    const int idx = (b*NHEADS + h)*SEQL + c*Q + t;
    dtc[idx] = dtv;
    clog[idx] = v;
}

// ---------------- G[t][s] = C_t . B_s  via MFMA; block covers 64 t x 128 s (bf16 in)
__global__ __launch_bounds__(256) void gcb_mfma(
    const ushort* __restrict__ xconv, ushort* __restrict__ G)
{
    __shared__ __align__(16) ushort Ca[64*32];
    __shared__ __align__(16) ushort Bb[128*32];
    const int thalf = blockIdx.x, c = blockIdx.y, b = blockIdx.z;
    const int tid = threadIdx.x;
    const int wv = tid >> 6, ln = tid & 63;
    const int fr = ln & 15, fq = ln >> 4, fk = fq*8;
    const int bl0 = b*SEQL + c*Q;
    const int th0 = thalf*64;

    const int sat = tid & 63,  sac = (tid >> 6)*8;
    const int sbt = tid & 127, sbh = (tid >> 7)*16;

    f32x4 acc[4][2];
#pragma unroll
    for (int i = 0; i < 4; ++i)
#pragma unroll
        for (int j = 0; j < 2; ++j) acc[i][j] = (f32x4){0.f,0.f,0.f,0.f};

    for (int ks = 0; ks < 4; ++ks) {
        uint4 av = *(const uint4*)(xconv + (size_t)(bl0 + th0 + sat)*CONVDIM + COFF + ks*32 + sac);
        const ushort* br = xconv + (size_t)(bl0 + sbt)*CONVDIM + BOFF + ks*32 + sbh;
        uint4 bv0 = *(const uint4*)br;
        uint4 bv1 = *(const uint4*)(br + 8);
        __syncthreads();
        *(uint4*)&Ca[sat*32 + sac] = av;
        *(uint4*)&Bb[sbt*32 + sbh] = bv0;
        *(uint4*)&Bb[sbt*32 + sbh + 8] = bv1;
        __syncthreads();
        bf16x8 av_[4], bv_[2];
#pragma unroll
        for (int i = 0; i < 4; ++i)
            av_[i] = *(const bf16x8*)&Ca[(i*16 + fr)*32 + fk];
#pragma unroll
        for (int j = 0; j < 2; ++j)
            bv_[j] = *(const bf16x8*)&Bb[(wv*32 + j*16 + fr)*32 + fk];
#pragma unroll
        for (int i = 0; i < 4; ++i)
#pragma unroll
            for (int j = 0; j < 2; ++j)
                acc[i][j] = __builtin_amdgcn_mfma_f32_16x16x32_bf16(av_[i], bv_[j], acc[i][j], 0, 0, 0);
    }
    ushort* gout = G + (size_t)(b*NC + c)*(Q*Q);
#pragma unroll
    for (int i = 0; i < 4; ++i) {
#pragma unroll
        for (int j = 0; j < 2; ++j) {
            const int s = wv*32 + j*16 + fr;
#pragma unroll
            for (int r = 0; r < 4; ++r) {
                const int t = th0 + i*16 + fq*4 + r;
                gout[t*Q + s] = f2bf(acc[i][j][r]);
            }
        }
    }
}

// ---------------- local chunk state via MFMA (bf16 in)
#define ASTR 40
#define BSTR 40
__global__ __launch_bounds__(256) void locstate_mfma(
    const ushort* __restrict__ xconv, const float* __restrict__ dtc,
    const float* __restrict__ clog, ushort* __restrict__ Sloc)
{
    __shared__ __align__(16) ushort Ab[64*ASTR];
    __shared__ __align__(16) ushort Bb[128*BSTR];
    __shared__ float sw[Q];
    const int c = blockIdx.x, h = blockIdx.y, b = blockIdx.z;
    const int tid = threadIdx.x;
    const int wv = tid >> 6, ln = tid & 63;
    const int fr = ln & 15, fq = ln >> 4, fk = fq*8;
    const int bh = b*NHEADS + h;
    const int bl0 = b*SEQL + c*Q;

    if (tid < Q) {
        const float ce = clog[(size_t)bh*SEQL + c*Q + (Q-1)];
        const float cs = clog[(size_t)bh*SEQL + c*Q + tid];
        sw[tid] = dtc[(size_t)bh*SEQL + c*Q + tid] * expf(ce - cs);
    }
    __syncthreads();

    f32x4 acc[4][2];
#pragma unroll
    for (int i = 0; i < 4; ++i)
#pragma unroll
        for (int j = 0; j < 2; ++j) acc[i][j] = (f32x4){0.f,0.f,0.f,0.f};

    const int ap = tid & 63, aoct = tid >> 6;
    const int bn = tid & 127, bhalf = tid >> 7;

    for (int ks = 0; ks < 4; ++ks) {
        float xv[8];
#pragma unroll
        for (int j = 0; j < 8; ++j) {
            const int s = ks*32 + aoct*8 + j;
            xv[j] = bf2f(xconv[(size_t)(bl0 + s)*CONVDIM + h*HEADDIM + ap]) * sw[s];
        }
        ushort bu[16];
#pragma unroll
        for (int j = 0; j < 16; ++j) {
            const int s = ks*32 + bhalf*16 + j;
            bu[j] = xconv[(size_t)(bl0 + s)*CONVDIM + BOFF + bn];
        }
        __syncthreads();
        *(uint4*)&Ab[ap*ASTR + aoct*8] =
            make_uint4(pack2(xv[0],xv[1]), pack2(xv[2],xv[3]),
                       pack2(xv[4],xv[5]), pack2(xv[6],xv[7]));
        *(uint4*)&Bb[bn*BSTR + bhalf*16] =
            make_uint4(packu2(bu[0],bu[1]), packu2(bu[2],bu[3]),
                       packu2(bu[4],bu[5]), packu2(bu[6],bu[7]));
        *(uint4*)&Bb[bn*BSTR + bhalf*16 + 8] =
            make_uint4(packu2(bu[8],bu[9]), packu2(bu[10],bu[11]),
                       packu2(bu[12],bu[13]), packu2(bu[14],bu[15]));
        __syncthreads();
        bf16x8 af[4], bf[2];
#pragma unroll
        for (int i = 0; i < 4; ++i)
            af[i] = *(const bf16x8*)&Ab[(i*16 + fr)*ASTR + fk];
#pragma unroll
        for (int j = 0; j < 2; ++j)
            bf[j] = *(const bf16x8*)&Bb[(wv*32 + j*16 + fr)*BSTR + fk];
#pragma unroll
        for (int i = 0; i < 4; ++i)
#pragma unroll
            for (int j = 0; j < 2; ++j)
                acc[i][j] = __builtin_amdgcn_mfma_f32_16x16x32_bf16(af[i], bf[j], acc[i][j], 0, 0, 0);
    }
    ushort* dst = Sloc + (size_t)((b*NC + c)*NHEADS + h) * (HEADDIM*DSTATE);
#pragma unroll
    for (int i = 0; i < 4; ++i) {
#pragma unroll
        for (int j = 0; j < 2; ++j) {
            const int n = wv*32 + j*16 + fr;
#pragma unroll
            for (int r = 0; r < 4; ++r) {
                const int p = i*16 + fq*4 + r;
                dst[p*DSTATE + n] = f2bf(acc[i][j][r]);
            }
        }
    }
}

// ---------------- in-place sequential prefix over chunk states; 4x p-split
__global__ __launch_bounds__(256) void chunkscan_kernel(
    const float* __restrict__ clog, ushort* __restrict__ S)
{
    const int h = blockIdx.x, b = blockIdx.y, pg = blockIdx.z;
    const int tid = threadIdx.x;
    const int p = pg*16 + (tid >> 4);
    const int n0 = (tid & 15) * 8;
    const int bh = b*NHEADS + h;
    float st[8];
#pragma unroll
    for (int j = 0; j < 8; ++j) st[j] = 0.f;

    for (int c = 0; c < NC; ++c) {
        const float tc = expf(clog[(size_t)bh*SEQL + c*Q + (Q-1)]);
        ushort* base = S + (size_t)((b*NC + c)*NHEADS + h) * (HEADDIM*DSTATE);
        uint4 raw = *(uint4*)(base + p*DSTATE + n0);
        float lv[8];
        unpack8(raw, lv);
        uint4 pre = make_uint4(pack2(st[0],st[1]), pack2(st[2],st[3]),
                               pack2(st[4],st[5]), pack2(st[6],st[7]));
        *(uint4*)(base + p*DSTATE + n0) = pre;
#pragma unroll
        for (int j = 0; j < 8; ++j) st[j] = fmaf(tc, st[j], lv[j]);
    }
}

// ---------------- Y = causal(G.W)@X + exp(clog)*C@Sp^T + D*x  — MFMA, bf16 out
__global__ __launch_bounds__(256) void ychunk_mfma(
    const ushort* __restrict__ xconv, const float* __restrict__ dtc,
    const float* __restrict__ clog, const ushort* __restrict__ G,
    const ushort* __restrict__ Sp, const float* __restrict__ Dv,
    ushort* __restrict__ ybf)
{
    __shared__ __align__(16) ushort smu[8192];  // Ab[128*32] + Bb[64*32]; rp aliases all
    ushort* Ab = smu;
    ushort* Bb = smu + 4096;
    __shared__ float s_clog[Q];
    __shared__ float s_dtc[Q];
    const int c = blockIdx.x, h = blockIdx.y, b = blockIdx.z;
    const int tid = threadIdx.x;
    const int wv = tid >> 6, ln = tid & 63;
    const int bh = b*NHEADS + h;
    const int bl0 = b*SEQL + c*Q;
    const int fr = ln & 15, fq = ln >> 4, fk = fq*8;

    if (tid < Q) {
        s_clog[tid] = clog[(size_t)bh*SEQL + c*Q + tid];
        s_dtc[tid]  = dtc [(size_t)bh*SEQL + c*Q + tid];
    }

    f32x4 acc[2][4];
#pragma unroll
    for (int i = 0; i < 2; ++i)
#pragma unroll
        for (int j = 0; j < 4; ++j) acc[i][j] = (f32x4){0.f,0.f,0.f,0.f};

    const int sgt = tid & 127, sgh = (tid >> 7)*16;
    const int sbp = tid & 63,  sbc = (tid >> 6)*8;
    const ushort* spb = Sp + (size_t)((b*NC + c)*NHEADS + h)*(HEADDIM*DSTATE);

    // phase 1: acc = C @ Sp^T
    for (int ks = 0; ks < 4; ++ks) {
        const ushort* cr = xconv + (size_t)(bl0 + sgt)*CONVDIM + COFF + ks*32 + sgh;
        uint4 cv0 = *(const uint4*)cr;
        uint4 cv1 = *(const uint4*)(cr + 8);
        uint4 sv = *(const uint4*)(spb + sbp*DSTATE + ks*32 + sbc);
        __syncthreads();
        *(uint4*)&Ab[sgt*32 + sgh]     = cv0;
        *(uint4*)&Ab[sgt*32 + sgh + 8] = cv1;
        *(uint4*)&Bb[sbp*32 + sbc] = sv;
        __syncthreads();
        bf16x8 af[2], bv[4];
        af[0] = *(const bf16x8*)&Ab[(wv*32 +      fr)*32 + fk];
        af[1] = *(const bf16x8*)&Ab[(wv*32 + 16 + fr)*32 + fk];
#pragma unroll
        for (int j = 0; j < 4; ++j)
            bv[j] = *(const bf16x8*)&Bb[(j*16 + fr)*32 + fk];
#pragma unroll
        for (int i = 0; i < 2; ++i)
#pragma unroll
            for (int j = 0; j < 4; ++j)
                acc[i][j] = __builtin_amdgcn_mfma_f32_16x16x32_bf16(af[i], bv[j], acc[i][j], 0, 0, 0);
    }
#pragma unroll
    for (int i = 0; i < 2; ++i) {
        const int tb = wv*32 + i*16 + fq*4;
        float e0 = expf(s_clog[tb+0]), e1 = expf(s_clog[tb+1]);
        float e2 = expf(s_clog[tb+2]), e3 = expf(s_clog[tb+3]);
#pragma unroll
        for (int j = 0; j < 4; ++j) {
            acc[i][j].x *= e0; acc[i][j].y *= e1; acc[i][j].z *= e2; acc[i][j].w *= e3;
        }
    }

    // phase 2: acc += (G .* W) @ X (causal)
    const ushort* gp = G + (size_t)(b*NC + c)*(Q*Q);
    for (int ks = 0; ks < 4; ++ks) {
        uint4 g0 = *(const uint4*)(gp + sgt*Q + ks*32 + sgh);
        uint4 g1 = *(const uint4*)(gp + sgt*Q + ks*32 + sgh + 8);
        ushort xu[8];
#pragma unroll
        for (int j = 0; j < 8; ++j)
            xu[j] = xconv[(size_t)(bl0 + ks*32 + sbc + j)*CONVDIM + h*HEADDIM + sbp];
        __syncthreads();
        {
            float gvals[16];
            unpack8(g0, gvals);
            unpack8(g1, gvals + 8);
            const float ct = s_clog[sgt];
            ushort gw[16];
#pragma unroll
            for (int j = 0; j < 16; ++j) {
                const int s = ks*32 + sgh + j;
                float w = 0.f;
                if (s <= sgt) w = s_dtc[s] * expf(ct - s_clog[s]);
                gw[j] = f2bf(gvals[j] * w);
            }
            *(uint4*)&Ab[sgt*32 + sgh] =
                make_uint4(packu2(gw[0],gw[1]), packu2(gw[2],gw[3]),
                           packu2(gw[4],gw[5]), packu2(gw[6],gw[7]));
            *(uint4*)&Ab[sgt*32 + sgh + 8] =
                make_uint4(packu2(gw[8],gw[9]), packu2(gw[10],gw[11]),
                           packu2(gw[12],gw[13]), packu2(gw[14],gw[15]));
            *(uint4*)&Bb[sbp*32 + sbc] =
                make_uint4(packu2(xu[0],xu[1]), packu2(xu[2],xu[3]),
                           packu2(xu[4],xu[5]), packu2(xu[6],xu[7]));
        }
        __syncthreads();
        if (ks <= wv) {
            bf16x8 af[2], bv[4];
            af[0] = *(const bf16x8*)&Ab[(wv*32 +      fr)*32 + fk];
            af[1] = *(const bf16x8*)&Ab[(wv*32 + 16 + fr)*32 + fk];
#pragma unroll
            for (int j = 0; j < 4; ++j)
                bv[j] = *(const bf16x8*)&Bb[(j*16 + fr)*32 + fk];
#pragma unroll
            for (int i = 0; i < 2; ++i)
#pragma unroll
                for (int j = 0; j < 4; ++j)
                    acc[i][j] = __builtin_amdgcn_mfma_f32_16x16x32_bf16(af[i], bv[j], acc[i][j], 0, 0, 0);
        }
    }

    // epilogue: + D*x, repack to bf16 via LDS (aliases Ab/Bb -> barrier first)
    const float Dh = Dv[h];
    __syncthreads();
    ushort* rp = smu;                      // 128 rows x 64 cols
#pragma unroll
    for (int i = 0; i < 2; ++i) {
#pragma unroll
        for (int r = 0; r < 4; ++r) {
            const int t = wv*32 + i*16 + fq*4 + r;
            const ushort* xr = xconv + (size_t)(bl0 + t)*CONVDIM + h*HEADDIM;
#pragma unroll
            for (int j = 0; j < 4; ++j) {
                const int p = j*16 + fr;
                rp[t*64 + p] = f2bf(acc[i][j][r] + Dh * bf2f(xr[p]));
            }
        }
    }
    // readback rows are this wave's own -> no barrier needed
#pragma unroll
    for (int k2 = 0; k2 < 4; ++k2) {
        const int row = wv*32 + k2*8 + (ln >> 3);
        uint4 v = *(const uint4*)&rp[row*64 + (ln & 7)*8];
        *(uint4*)(ybf + (size_t)(bl0 + row)*DINNER + h*HEADDIM + (ln & 7)*8) = v;
    }
}

// ---------------- gated RMSNorm, bf16 in/out (in place on ybf)
__global__ __launch_bounds__(128) void rms_kernel(
    const ushort* __restrict__ zx, const float* __restrict__ norm_w,
    ushort* __restrict__ ybf)
{
    const int row = blockIdx.x;
    const int tid = threadIdx.x;
    const ushort* zr = zx + (size_t)row * DINPROJ;
    ushort* yr = ybf + (size_t)row * DINNER;
    float v[12];
    float ss = 0.f;
#pragma unroll
    for (int i = 0; i < 3; ++i) {
        const int o = (tid + i*128) * 4;
        ushort4 yv = *(const ushort4*)(yr + o);
        ushort4 zv = *(const ushort4*)(zr + o);
        float a = bf2f(yv.x) * siluf_(bf2f(zv.x));
        float b = bf2f(yv.y) * siluf_(bf2f(zv.y));
        float cc = bf2f(yv.z) * siluf_(bf2f(zv.z));
        float d = bf2f(yv.w) * siluf_(bf2f(zv.w));
        v[i*4+0]=a; v[i*4+1]=b; v[i*4+2]=cc; v[i*4+3]=d;
        ss += a*a + b*b + cc*cc + d*d;
    }
#pragma unroll
    for (int off = 1; off < 64; off <<= 1) ss += __shfl_xor(ss, off);
    __shared__ float red[2];
    if ((tid & 63) == 0) red[tid >> 6] = ss;
    __syncthreads();
    const float rstd = rsqrtf((red[0] + red[1]) * (1.f/DINNER) + RMS_EPS);
#pragma unroll
    for (int i = 0; i < 3; ++i) {
        const int o = (tid + i*128) * 4;
        float4 wv = *(const float4*)(norm_w + o);
        ushort4 ov = make_ushort4(f2bf(v[i*4+0]*rstd*wv.x), f2bf(v[i*4+1]*rstd*wv.y),
                                  f2bf(v[i*4+2]*rstd*wv.z), f2bf(v[i*4+3]*rstd*wv.w));
        *(ushort4*)(yr + o) = ov;
    }
}

extern "C" void kernel_launch(void* const* d_in, const int* in_sizes, int n_in,
                              void* d_out, int out_size, void* d_ws, size_t ws_size,
                              hipStream_t stream)
{
    const float* feature    = (const float*)d_in[0];
    const float* in_proj_w  = (const float*)d_in[1];
    const float* conv_w     = (const float*)d_in[2];
    const float* conv_b     = (const float*)d_in[3];
    const float* dt_bias    = (const float*)d_in[4];
    const float* A_log      = (const float*)d_in[5];
    const float* Dvec       = (const float*)d_in[6];
    const float* norm_w     = (const float*)d_in[7];
    const float* out_proj_w = (const float*)d_in[8];
    const float* gate1      = (const float*)d_in[9];
    float* out = (float*)d_out;

    ushort* zx    = (ushort*)d_ws;                              // [8192,3352] bf16
    ushort* xconv = zx + (size_t)BLROWS * DINPROJ;              // [8192,1792] bf16
    ushort* ybf   = xconv + (size_t)BLROWS * CONVDIM;           // [8192,1536] bf16
    float* dtraw  = (float*)(ybf + (size_t)BLROWS * DINNER);    // [8192,24]
    float* dtc    = dtraw + (size_t)BLROWS * 24;
    float* clog   = dtc + (size_t)NB * NHEADS * SEQL;
    ushort* Gbuf  = (ushort*)(clog + (size_t)NB * NHEADS * SEQL);  // 2 MB
    ushort* Sbuf  = Gbuf + (size_t)NB * NC * Q * Q;                // 25 MB
    ushort* Abf    = Gbuf;                            // feature bf16 (dead after gemm1)
    ushort* Wbf_in = Gbuf + (size_t)BLROWS * DMODEL;  // in_proj_w bf16 (dead after gemm1)
    ushort* Wbf_out = zx;                             // out_proj_w bf16 (after rms)

    cast_kernel<<<dim3((BLROWS*DMODEL/4 + 255)/256), 256, 0, stream>>>(feature, Abf, BLROWS*DMODEL/4);
    cast_kernel<<<dim3((DINPROJ*DMODEL/4 + 255)/256), 256, 0, stream>>>(in_proj_w, Wbf_in, DINPROJ*DMODEL/4);
    gemm_mfma_bf16o<<<dim3(64, 27), 256, 0, stream>>>(Abf, Wbf_in, zx, dtraw,
                                                      BLROWS, DINPROJ, DMODEL);
    conv_kernel<<<dim3(BLROWS), 448, 0, stream>>>(zx, conv_w, conv_b, xconv);
    dtscan_kernel<<<dim3(NC, NHEADS, NB), 128, 0, stream>>>(dtraw, dt_bias, A_log, dtc, clog);
    gcb_mfma<<<dim3(2, NC, NB), 256, 0, stream>>>(xconv, Gbuf);
    locstate_mfma<<<dim3(NC, NHEADS, NB), 256, 0, stream>>>(xconv, dtc, clog, Sbuf);
    chunkscan_kernel<<<dim3(NHEADS, NB, 4), 256, 0, stream>>>(clog, Sbuf);
    ychunk_mfma<<<dim3(NC, NHEADS, NB), 256, 0, stream>>>(xconv, dtc, clog, Gbuf, Sbuf, Dvec, ybf);
    rms_kernel<<<dim3(BLROWS), 128, 0, stream>>>(zx, norm_w, ybf);
    cast_kernel<<<dim3((DMODEL*DINNER/4 + 255)/256), 256, 0, stream>>>(out_proj_w, Wbf_out, DMODEL*DINNER/4);
    gemm_mfma<<<dim3(64, 6), 256, 0, stream>>>(ybf, Wbf_out, out,
                                               BLROWS, DMODEL, DINNER, gate1);
}